// Round 13
// baseline (408.886 us; speedup 1.0000x reference)
//
#include <hip/hip_runtime.h>
#include <stdint.h>

// PointerNetwork forward, MI355X/gfx950 — 4-way phase split for attribution.
// R12 post-mortem: the L2-weight-refetch model was falsified (pass-split and
// PIN both failed to move time). Splitting mega at phase boundaries gives
// per-dispatch rocprof timing of chains (kA) vs prep (kB) vs scores (kC) vs
// sampling (kD), plus lets kC run at 2-3 blocks/CU (mega forced 1).
// B=256, S=64, H=128.
// RNG: JAX threefry2x32 partitionable mode: bits = o0^o1 of tf(key,(0,j)).

#define BN 256
#define SN 64
#define HN 128
#define NEGV (-1.0e9f)
#define TINYF 1.17549435e-38f

__device__ __forceinline__ uint32_t rotl32(uint32_t v, int d) {
  return (v << d) | (v >> (32 - d));
}

__device__ __forceinline__ void threefry2x32(uint32_t k0, uint32_t k1,
                                             uint32_t x0, uint32_t x1,
                                             uint32_t& o0, uint32_t& o1) {
  uint32_t ks2 = k0 ^ k1 ^ 0x1BD11BDAu;
  x0 += k0; x1 += k1;
  x0 += x1; x1 = rotl32(x1, 13); x1 ^= x0;
  x0 += x1; x1 = rotl32(x1, 15); x1 ^= x0;
  x0 += x1; x1 = rotl32(x1, 26); x1 ^= x0;
  x0 += x1; x1 = rotl32(x1, 6);  x1 ^= x0;
  x0 += k1; x1 += ks2 + 1u;
  x0 += x1; x1 = rotl32(x1, 17); x1 ^= x0;
  x0 += x1; x1 = rotl32(x1, 29); x1 ^= x0;
  x0 += x1; x1 = rotl32(x1, 16); x1 ^= x0;
  x0 += x1; x1 = rotl32(x1, 24); x1 ^= x0;
  x0 += ks2; x1 += k0 + 2u;
  x0 += x1; x1 = rotl32(x1, 13); x1 ^= x0;
  x0 += x1; x1 = rotl32(x1, 15); x1 ^= x0;
  x0 += x1; x1 = rotl32(x1, 26); x1 ^= x0;
  x0 += x1; x1 = rotl32(x1, 6);  x1 ^= x0;
  x0 += k0; x1 += k1 + 3u;
  x0 += x1; x1 = rotl32(x1, 17); x1 ^= x0;
  x0 += x1; x1 = rotl32(x1, 29); x1 ^= x0;
  x0 += x1; x1 = rotl32(x1, 16); x1 ^= x0;
  x0 += x1; x1 = rotl32(x1, 24); x1 ^= x0;
  x0 += k1; x1 += ks2 + 4u;
  x0 += x1; x1 = rotl32(x1, 13); x1 ^= x0;
  x0 += x1; x1 = rotl32(x1, 15); x1 ^= x0;
  x0 += x1; x1 = rotl32(x1, 26); x1 ^= x0;
  x0 += x1; x1 = rotl32(x1, 6);  x1 ^= x0;
  x0 += ks2; x1 += k0 + 5u;
  o0 = x0; o1 = x1;
}

__device__ __forceinline__ float jax_gumbel(uint32_t k0, uint32_t k1, int j) {
  uint32_t o0, o1;
  threefry2x32(k0, k1, 0u, (uint32_t)j, o0, o1);
  uint32_t bits = o0 ^ o1;
  uint32_t ub = (bits >> 9) | 0x3F800000u;
  float u = __uint_as_float(ub) - 1.0f;
  u = fmaxf(u + TINYF, TINYF);
  return -logf(-logf(u));
}

__device__ __forceinline__ float ftanh(float x) {
  float ax = fabsf(x);
  float e = __expf(-2.0f * ax);
  float r = (1.0f - e) * __builtin_amdgcn_rcpf(1.0f + e);
  return copysignf(r, x);
}

__device__ __forceinline__ float fsig(float x) {
  return __builtin_amdgcn_rcpf(1.0f + __expf(-x));
}

// ---------------- K0: fold dyn path + step keys ----------------
__global__ void k0_dyn(const float* __restrict__ W_att, const float* __restrict__ dyn_w,
                       const float* __restrict__ dyn_b, float* __restrict__ Wd,
                       float* __restrict__ cv, uint32_t* __restrict__ keys) {
  int h = threadIdx.x;  // 128
  if (h < 64) {
    uint32_t o0, o1;
    threefry2x32(0u, 42u, 0u, (uint32_t)h, o0, o1);
    keys[2 * h] = o0; keys[2 * h + 1] = o1;
  }
  float w0 = 0.f, w1 = 0.f, cc = 0.f;
  for (int k = 0; k < HN; ++k) {
    float w = W_att[h * 384 + 128 + k];
    w0 = fmaf(w, dyn_w[2 * k + 0], w0);
    w1 = fmaf(w, dyn_w[2 * k + 1], w1);
    cc = fmaf(w, dyn_b[k], cc);
  }
  Wd[2 * h] = w0; Wd[2 * h + 1] = w1; cv[h] = cc;
}

// ---------------- kA: chains (P0 x-chain, P1 GI 4-pass, P2 GRU) -> H_g ------
// LDS: A(X) 8192 @0, GIl 24576 @8192, HC 256 @32768  => 132096 B
__global__ __launch_bounds__(512)
__attribute__((amdgpu_waves_per_eu(2, 2)))
void kA(const float* __restrict__ SE,
        const float* __restrict__ in_w, const float* __restrict__ in_b,
        const float* __restrict__ w_ih, const float* __restrict__ b_ih,
        const float* __restrict__ w_hh, const float* __restrict__ b_hh,
        float* __restrict__ H_g) {
  extern __shared__ float sm[];
  float* A   = sm;
  float* GIl = sm + 8192;
  float* HC  = sm + 32768;
  int b = blockIdx.x, t = threadIdx.x;
  if (t < 128) HC[t] = SE[b * 8192 + t * 64];  // x_{-1} = SE[b,:,0]
  __syncthreads();

  // ---- P0: x-chain. 128 ml x 4 ks; 32 weight floats (resident) ----
  {
    int ml = t >> 2, ks = t & 3;
    float4 wv[8];
#pragma unroll
    for (int q = 0; q < 8; ++q)
      wv[q] = *(const float4*)(in_w + ml * HN + q * 16 + ks * 4);
    float bib = in_b[ml];
    for (int ii = 0; ii < SN; ++ii) {
      const float* xc = HC + (ii & 1) * 128;
      float* xn = HC + ((ii + 1) & 1) * 128;
      float a0 = 0.f, a1 = 0.f, a2 = 0.f, a3 = 0.f;
#pragma unroll
      for (int q = 0; q < 8; ++q) {
        float4 x4 = *(const float4*)(xc + q * 16 + ks * 4);
        a0 = fmaf(wv[q].x, x4.x, a0);
        a1 = fmaf(wv[q].y, x4.y, a1);
        a2 = fmaf(wv[q].z, x4.z, a2);
        a3 = fmaf(wv[q].w, x4.w, a3);
      }
      float s = (a0 + a1) + (a2 + a3);
      s += __shfl_xor(s, 1); s += __shfl_xor(s, 2);
      if (ks == 0) {
        float xv = s + bib;
        A[ii * 128 + ml] = xv;
        xn[ml] = xv;
      }
      __syncthreads();
    }
  }

  // ---- P1: GI = w_ih @ X + b_ih. FOUR 32-k passes, 24 wt floats/pass ----
  {
    int ml = t >> 2, ks = t & 3;
    float bi[3];
#pragma unroll
    for (int j = 0; j < 3; ++j) bi[j] = b_ih[ml + 128 * j];
#pragma unroll
    for (int p = 0; p < 4; ++p) {
      float4 wv[3][2];
#pragma unroll
      for (int j = 0; j < 3; ++j)
#pragma unroll
        for (int q = 0; q < 2; ++q)
          wv[j][q] = *(const float4*)(w_ih + (ml + 128 * j) * HN + p * 32 + q * 16 + ks * 4);
      for (int n = 0; n < SN; ++n) {
        float4 x0 = *(const float4*)(A + n * 128 + p * 32 + ks * 4);
        float4 x1 = *(const float4*)(A + n * 128 + p * 32 + 16 + ks * 4);
#pragma unroll
        for (int j = 0; j < 3; ++j) {
          float a0 = fmaf(wv[j][0].x, x0.x, 0.f);
          float a1 = fmaf(wv[j][0].y, x0.y, 0.f);
          float a2 = fmaf(wv[j][0].z, x0.z, 0.f);
          float a3 = fmaf(wv[j][0].w, x0.w, 0.f);
          a0 = fmaf(wv[j][1].x, x1.x, a0);
          a1 = fmaf(wv[j][1].y, x1.y, a1);
          a2 = fmaf(wv[j][1].z, x1.z, a2);
          a3 = fmaf(wv[j][1].w, x1.w, a3);
          float s = (a0 + a1) + (a2 + a3);
          s += __shfl_xor(s, 1); s += __shfl_xor(s, 2);
          if (ks == 0) {
            int idx = n * 384 + ml + 128 * j;
            if (p == 0) GIl[idx] = s;
            else if (p == 3) GIl[idx] = GIl[idx] + s + bi[j];
            else GIl[idx] += s;
          }
        }
      }
    }
    __syncthreads();
  }

  // ---- P2: h-chain (GRU). 128 ml x 4 ks; rows ml+128j; lane-local tail ----
  if (t < 256) HC[t] = 0.f;
  __syncthreads();
  {
    int ml = t >> 2, ks = t & 3;
    float4 wv[3][8]; float bh[3];
#pragma unroll
    for (int j = 0; j < 3; ++j) {
#pragma unroll
      for (int q = 0; q < 8; ++q)
        wv[j][q] = *(const float4*)(w_hh + (ml + 128 * j) * HN + q * 16 + ks * 4);
      bh[j] = b_hh[ml + 128 * j];
    }
    float hp = 0.f;
    for (int ii = 0; ii < SN; ++ii) {
      const float* hcr = HC + (ii & 1) * 128;
      float* hcw = HC + ((ii + 1) & 1) * 128;
      float4 x4[8];
#pragma unroll
      for (int q = 0; q < 8; ++q)
        x4[q] = *(const float4*)(hcr + q * 16 + ks * 4);
      float sum[3];
#pragma unroll
      for (int j = 0; j < 3; ++j) {
        float a0 = 0.f, a1 = 0.f, a2 = 0.f, a3 = 0.f;
#pragma unroll
        for (int q = 0; q < 8; ++q) {
          a0 = fmaf(wv[j][q].x, x4[q].x, a0);
          a1 = fmaf(wv[j][q].y, x4[q].y, a1);
          a2 = fmaf(wv[j][q].z, x4[q].z, a2);
          a3 = fmaf(wv[j][q].w, x4[q].w, a3);
        }
        float s = (a0 + a1) + (a2 + a3);
        s += __shfl_xor(s, 1); s += __shfl_xor(s, 2);
        sum[j] = s + bh[j];
      }
      if (ks == 0) {
        const float* gr = GIl + ii * 384;
        float r = fsig(gr[ml] + sum[0]);
        float z = fsig(gr[128 + ml] + sum[1]);
        float nn = ftanh(gr[256 + ml] + r * sum[2]);
        float hn = (1.0f - z) * nn + z * hp;
        hcw[ml] = hn;
        H_g[(b * SN + ii) * HN + ml] = hn;
        hp = hn;
      }
      __syncthreads();
    }
  }
}

// ---------------- kB: WhC + Ust prep -> WHC_g, UT_g ----------------
// LDS: A(H) 8192 @0, SET 8448 @8192, UT 8448 @16640 => 100352 B
__global__ __launch_bounds__(512) void kB(
    const float* __restrict__ SE, const float* __restrict__ dynamic,
    const float* __restrict__ W_att,
    const float* __restrict__ Wd, const float* __restrict__ cv,
    const float* __restrict__ H_g,
    float* __restrict__ WHC_g, float* __restrict__ UT_g) {
  extern __shared__ float sm[];
  float* A   = sm;
  float* SET = sm + 8192;
  float* UT  = sm + 16640;
  int b = blockIdx.x, t = threadIdx.x;
#pragma unroll
  for (int p = 0; p < 4; ++p)
    ((float4*)A)[p * 512 + t] = ((const float4*)(H_g + b * 8192))[p * 512 + t];
  __syncthreads();

  // ---- P3: WhC = W_att3 @ H. 64 ml x 8 ks; 2 m-rows ----
  {
    int ml = t >> 3, ks = t & 7;
    float4 w0[4], w1[4];
#pragma unroll
    for (int q = 0; q < 4; ++q) {
      w0[q] = *(const float4*)(W_att + (ml)      * 384 + 256 + q * 32 + ks * 4);
      w1[q] = *(const float4*)(W_att + (ml + 64) * 384 + 256 + q * 32 + ks * 4);
    }
    for (int n = 0; n < SN; ++n) {
      float4 x4[4];
#pragma unroll
      for (int q = 0; q < 4; ++q)
        x4[q] = *(const float4*)(A + n * 128 + q * 32 + ks * 4);
      float a00 = 0.f, a01 = 0.f, a10 = 0.f, a11 = 0.f;
#pragma unroll
      for (int q = 0; q < 4; ++q) {
        a00 = fmaf(w0[q].x, x4[q].x, a00);
        a01 = fmaf(w0[q].y, x4[q].y, a01);
        a00 = fmaf(w0[q].z, x4[q].z, a00);
        a01 = fmaf(w0[q].w, x4[q].w, a01);
        a10 = fmaf(w1[q].x, x4[q].x, a10);
        a11 = fmaf(w1[q].y, x4[q].y, a11);
        a10 = fmaf(w1[q].z, x4[q].z, a10);
        a11 = fmaf(w1[q].w, x4[q].w, a11);
      }
      float s0 = a00 + a01, s1 = a10 + a11;
      s0 += __shfl_xor(s0, 1); s0 += __shfl_xor(s0, 2); s0 += __shfl_xor(s0, 4);
      s1 += __shfl_xor(s1, 1); s1 += __shfl_xor(s1, 2); s1 += __shfl_xor(s1, 4);
      if (ks == 0) {
        WHC_g[(b * SN + n) * HN + ml] = s0;
        WHC_g[(b * SN + n) * HN + ml + 64] = s1;
      }
    }
  }

  // ---- P4: stage SE[b] transposed: SET[s][132] = SE[b][h][s] ----
  for (int p = 0; p < 16; ++p) {
    int idx = p * 512 + t;
    int h = idx >> 6, s = idx & 63;
    SET[s * 132 + h] = SE[b * 8192 + idx];
  }
  __syncthreads();

  // ---- P5: U_t[m][66] = (W_att1 @ SE^T)[s][m] + dyn-fold ----
  {
    int ml = t >> 3, ks = t & 7;
    float4 w0[4], w1[4];
#pragma unroll
    for (int q = 0; q < 4; ++q) {
      w0[q] = *(const float4*)(W_att + (ml)      * 384 + q * 32 + ks * 4);
      w1[q] = *(const float4*)(W_att + (ml + 64) * 384 + q * 32 + ks * 4);
    }
    for (int n = 0; n < SN; ++n) {
      float4 x4[4];
#pragma unroll
      for (int q = 0; q < 4; ++q)
        x4[q] = *(const float4*)(SET + n * 132 + q * 32 + ks * 4);
      float a00 = 0.f, a01 = 0.f, a10 = 0.f, a11 = 0.f;
#pragma unroll
      for (int q = 0; q < 4; ++q) {
        a00 = fmaf(w0[q].x, x4[q].x, a00);
        a01 = fmaf(w0[q].y, x4[q].y, a01);
        a00 = fmaf(w0[q].z, x4[q].z, a00);
        a01 = fmaf(w0[q].w, x4[q].w, a01);
        a10 = fmaf(w1[q].x, x4[q].x, a10);
        a11 = fmaf(w1[q].y, x4[q].y, a11);
        a10 = fmaf(w1[q].z, x4[q].z, a10);
        a11 = fmaf(w1[q].w, x4[q].w, a11);
      }
      float s0 = a00 + a01, s1 = a10 + a11;
      s0 += __shfl_xor(s0, 1); s0 += __shfl_xor(s0, 2); s0 += __shfl_xor(s0, 4);
      s1 += __shfl_xor(s1, 1); s1 += __shfl_xor(s1, 2); s1 += __shfl_xor(s1, 4);
      if (ks == 0) {
        float d0 = dynamic[b * 128 + n], d1 = dynamic[b * 128 + 64 + n];
        UT[(ml)      * 66 + n] = s0 + Wd[2 * ml] * d0 + Wd[2 * ml + 1] * d1 + cv[ml];
        UT[(ml + 64) * 66 + n] = s1 + Wd[2 * (ml + 64)] * d0 + Wd[2 * (ml + 64) + 1] * d1 + cv[ml + 64];
      }
    }
    __syncthreads();
  }
  // copy UT (incl pad) out coalesced
  for (int idx = t; idx < 8448; idx += 512) UT_g[b * 8448 + idx] = UT[idx];
}

// ---------------- kC: scores + gumbels, grid (256, 2) ----------------
__global__ __launch_bounds__(256) void kC(
    const float* __restrict__ UT_g, const float* __restrict__ WHC_g,
    const float* __restrict__ v_att, const uint32_t* __restrict__ keys,
    float* __restrict__ P_g, float* __restrict__ G_g) {
  __shared__ float UTl[8448];
  __shared__ float WH[32 * HN];
  __shared__ float SVl[HN];
  int b = blockIdx.x, y = blockIdx.y, t = threadIdx.x;
  for (int idx = t; idx < 8448; idx += 256) UTl[idx] = UT_g[b * 8448 + idx];
  for (int idx = t; idx < 4096; idx += 256)
    WH[idx] = WHC_g[(b * SN + y * 32) * HN + idx];
  if (t < HN) SVl[t] = v_att[t];
  __syncthreads();
  int s = t & 63, w = t >> 6;   // 4 waves; wave w owns i = y*32 + w*8 + j
  float acc[8];
#pragma unroll
  for (int j = 0; j < 8; ++j) acc[j] = 0.f;
  for (int h = 0; h < HN; h += 4) {
    float u0 = UTl[(h + 0) * 66 + s];
    float u1 = UTl[(h + 1) * 66 + s];
    float u2 = UTl[(h + 2) * 66 + s];
    float u3 = UTl[(h + 3) * 66 + s];
    float4 v4 = *(const float4*)(SVl + h);
#pragma unroll
    for (int j = 0; j < 8; ++j) {
      float4 wh = *(const float4*)(WH + (w * 8 + j) * HN + h);
      float a = acc[j];
      a = fmaf(v4.x, ftanh(u0 + wh.x), a);
      a = fmaf(v4.y, ftanh(u1 + wh.y), a);
      a = fmaf(v4.z, ftanh(u2 + wh.z), a);
      a = fmaf(v4.w, ftanh(u3 + wh.w), a);
      acc[j] = a;
    }
  }
#pragma unroll
  for (int j = 0; j < 8; ++j)
    P_g[b * 4096 + (y * 32 + w * 8 + j) * 64 + s] = acc[j];
  // gumbels for this half's i-range
  for (int p = 0; p < 8; ++p) {
    int idx = p * 256 + t;           // < 2048
    int i = y * 32 + (idx >> 6);
    int s2 = idx & 63;
    G_g[b * 4096 + i * 64 + s2] = jax_gumbel(keys[2 * i], keys[2 * i + 1], b * 64 + s2);
  }
}

// ---------------- kD: sampling ----------------
__global__ __launch_bounds__(256) void kD(const float* __restrict__ P_g,
                                          const float* __restrict__ G_g,
                                          float* __restrict__ out) {
  __shared__ float Pl[4096];
  __shared__ float Gl[4096];
  int b = blockIdx.x, t = threadIdx.x;
#pragma unroll
  for (int p = 0; p < 4; ++p) {
    ((float4*)Pl)[p * 256 + t] = ((const float4*)(P_g + b * 4096))[p * 256 + t];
    ((float4*)Gl)[p * 256 + t] = ((const float4*)(G_g + b * 4096))[p * 256 + t];
  }
  __syncthreads();
  if (t < 64) {
    int s = t;
    bool visited = false;
    for (int i = 0; i < SN; ++i) {
      float score = Pl[i * 64 + s];
      bool allowed = (i == 0) ? (s == 0) : (!visited);
      float logit = allowed ? score : NEGV;
      float z = logit + Gl[i * 64 + s];
      float bz = z; int bi = s;
#pragma unroll
      for (int off = 32; off > 0; off >>= 1) {
        float oz = __shfl_xor(bz, off);
        int oi = __shfl_xor(bi, off);
        if (oz > bz || (oz == bz && oi < bi)) { bz = oz; bi = oi; }
      }
      int ptr = bi;
      float m = logit;
#pragma unroll
      for (int off = 32; off > 0; off >>= 1) m = fmaxf(m, __shfl_xor(m, off));
      float e = expf(logit - m);
      float sum = e;
#pragma unroll
      for (int off = 32; off > 0; off >>= 1) sum += __shfl_xor(sum, off);
      float chosen = __shfl(logit, ptr);
      float logp = (chosen - m) - logf(sum);
      if (s == ptr) visited = true;
      if (s == 0) {
        out[b * SN + i] = (float)ptr;
        out[BN * SN + b * SN + i] = logp;
      }
    }
  }
}

// ---------------- launch ----------------
extern "C" void kernel_launch(void* const* d_in, const int* in_sizes, int n_in,
                              void* d_out, int out_size, void* d_ws, size_t ws_size,
                              hipStream_t stream) {
  const float* SE    = (const float*)d_in[1];
  const float* dynam = (const float*)d_in[2];
  const float* dyn_w = (const float*)d_in[3];
  const float* dyn_b = (const float*)d_in[4];
  const float* in_w  = (const float*)d_in[5];
  const float* in_b  = (const float*)d_in[6];
  const float* w_ih  = (const float*)d_in[7];
  const float* w_hh  = (const float*)d_in[8];
  const float* b_ih  = (const float*)d_in[9];
  const float* b_hh  = (const float*)d_in[10];
  const float* W_att = (const float*)d_in[11];
  const float* v_att = (const float*)d_in[12];
  float* out = (float*)d_out;
  float* ws = (float*)d_ws;

  // workspace (floats), lifetime-aliased:
  //  H_g @0 (2M) — dead after kB; P_g @0 (1M), G_g @1M (1M) reuse it for kC/kD
  //  WHC_g @2M (2M); UT_g @4M (2.16M); Wd/cv/keys @6.36M
  float* H_g   = ws;
  float* P_g   = ws;
  float* G_g   = ws + 1048576;
  float* WHC_g = ws + 2097152;
  float* UT_g  = ws + 4194304;
  float* Wd    = ws + 6356992;
  float* cv    = Wd + 256;
  uint32_t* keys = (uint32_t*)(cv + 128);

  (void)hipFuncSetAttribute((const void*)kA,
                            hipFuncAttributeMaxDynamicSharedMemorySize, 132096);
  (void)hipFuncSetAttribute((const void*)kB,
                            hipFuncAttributeMaxDynamicSharedMemorySize, 100352);

  hipLaunchKernelGGL(k0_dyn, dim3(1), dim3(128), 0, stream,
                     W_att, dyn_w, dyn_b, Wd, cv, keys);
  hipLaunchKernelGGL(kA, dim3(BN), dim3(512), 132096, stream,
                     SE, in_w, in_b, w_ih, b_ih, w_hh, b_hh, H_g);
  hipLaunchKernelGGL(kB, dim3(BN), dim3(512), 100352, stream,
                     SE, dynam, W_att, Wd, cv, H_g, WHC_g, UT_g);
  hipLaunchKernelGGL(kC, dim3(BN, 2), dim3(256), 0, stream,
                     UT_g, WHC_g, v_att, keys, P_g, G_g);
  hipLaunchKernelGGL(kD, dim3(BN), dim3(256), 0, stream, P_g, G_g, out);
}